// Round 2
// baseline (83.682 us; speedup 1.0000x reference)
//
#include <hip/hip_runtime.h>
#include <cstddef>
#include <cmath>

#define SEQ    1024
#define CH     64
#define UNITS  32
#define WIDTH  64
#define HALFW  32
#define BATCH  4
#define EPS    1e-7f

#define TS     8          // s-tile per block
#define TT     72         // t-extent staged: TS + 63, padded to 72
#define XS     76         // LDS row stride: float4-aligned; 76r%32 -> 2-way alias (free)
#define SCS    65         // LDS row stride for score tile

// Workspace-free plan: q2/k2 (2*B*U*S = 262144 floats) live in the v-region of
// out (B*C*S = 262144 floats) and are overwritten by the real v at the end.
//   k1: x -> q2 = 2*(q+bh), k2 = 2*k        (writes out[0..262143])
//   k2: q2,k2 -> a                          (writes out[262144..])
//   k3: a,x  -> v                           (overwrites out[0..262143])
// Inner loop identity: score = (Swa + Wa_b) + sum_u (-2*wa_u) * rcp(exp(2z)+1);
// the per-row constant cancels in softmax, so we never compute it.

// ---------------- Kernel 1: scaled q/k projections ----------------
__global__ __launch_bounds__(256) void qk_kernel(
    const float* __restrict__ x, const float* __restrict__ Wt,
    const float* __restrict__ Wx, const float* __restrict__ bh,
    float* __restrict__ q2, float* __restrict__ k2)
{
    int bu = blockIdx.x;                 // b*UNITS + u
    int u  = bu & (UNITS - 1);
    int b  = bu >> 5;
    int s4 = (int)threadIdx.x << 2;

    const float* wt = Wt + u * CH;
    const float* wx = Wx + u * CH;
    const float* xb = x + (size_t)b * CH * SEQ + s4;

    float4 qa = {0.f, 0.f, 0.f, 0.f};
    float4 ka = {0.f, 0.f, 0.f, 0.f};
#pragma unroll
    for (int c = 0; c < CH; ++c) {
        float4 xv = *reinterpret_cast<const float4*>(xb + (size_t)c * SEQ);
        float wtc = wt[c], wxc = wx[c];
        qa.x = fmaf(xv.x, wtc, qa.x); qa.y = fmaf(xv.y, wtc, qa.y);
        qa.z = fmaf(xv.z, wtc, qa.z); qa.w = fmaf(xv.w, wtc, qa.w);
        ka.x = fmaf(xv.x, wxc, ka.x); ka.y = fmaf(xv.y, wxc, ka.y);
        ka.z = fmaf(xv.z, wxc, ka.z); ka.w = fmaf(xv.w, wxc, ka.w);
    }
    float bhu = bh[u];
    qa.x = 2.f * (qa.x + bhu); qa.y = 2.f * (qa.y + bhu);
    qa.z = 2.f * (qa.z + bhu); qa.w = 2.f * (qa.w + bhu);
    ka.x *= 2.f; ka.y *= 2.f; ka.z *= 2.f; ka.w *= 2.f;

    size_t o = (size_t)bu * SEQ + s4;
    *reinterpret_cast<float4*>(q2 + o) = qa;
    *reinterpret_cast<float4*>(k2 + o) = ka;
}

// ---------------- Kernel 2: windowed scores + softmax + a-write ----------
__global__ __launch_bounds__(256) void score_kernel(
    const float* __restrict__ q2, const float* __restrict__ k2,
    const float* __restrict__ Wa_w, float* __restrict__ aout)
{
    __shared__ float kt[UNITS * XS];    // k2[b][u][t0+tt]
    __shared__ float qt[UNITS * TS];    // q2[b][u][s0+sl]
    __shared__ float sc[TS * SCS];      // scores -> a
    __shared__ float wa_s[UNITS];       // -2*wa

    int tid = threadIdx.x;
    int blk = blockIdx.x;
    int b   = blk >> 7;                 // SEQ/TS = 128 tiles per batch
    int s0  = (blk & 127) << 3;
    int t0  = s0 - HALFW;

    const float* qb = q2 + (size_t)b * UNITS * SEQ;
    const float* kb = k2 + (size_t)b * UNITS * SEQ;

    // ---- stage ----
    {
        int u = tid >> 3, sl = tid & 7;
        qt[u * TS + sl] = qb[u * SEQ + s0 + sl];
    }
    if (tid < UNITS) wa_s[tid] = -2.f * Wa_w[tid];

    if (t0 >= 0 && t0 + TT <= SEQ) {
        // interior: vectorized, 32 rows x 18 float4 = 576 loads
#pragma unroll
        for (int i = 0; i < 3; ++i) {
            int idx = i * 256 + tid;
            if (idx < UNITS * 18) {
                int u = idx / 18, p = idx - u * 18;
                float4 v4 = *reinterpret_cast<const float4*>(kb + u * SEQ + t0 + (p << 2));
                *reinterpret_cast<float4*>(&kt[u * XS + (p << 2)]) = v4;
            }
        }
    } else {
        // edge tiles (8 per batch): scalar with clamp
#pragma unroll
        for (int i = 0; i < 9; ++i) {   // 32*72 = 2304 = 9*256
            int idx = i * 256 + tid;
            int u = idx / TT, tt = idx - u * TT;
            int t = t0 + tt; t = t < 0 ? 0 : (t >= SEQ ? SEQ - 1 : t);
            kt[u * XS + tt] = kb[u * SEQ + t];
        }
    }
    __syncthreads();

    // ---- scores: thread -> (sl = tid>>5, tl in {tid&31, +32}) ----
    {
        int sl = tid >> 5, tlg = tid & 31;
        float e0 = 0.f, e1 = 0.f;
#pragma unroll
        for (int u = 0; u < UNITS; ++u) {
            float qv = qt[u * TS + sl];
            float k0 = kt[u * XS + sl + tlg];
            float k1 = kt[u * XS + sl + tlg + 32];
            float wa = wa_s[u];
            // score += wa_u * tanh(z)  ==  const + (-2*wa_u) * rcp(exp(2z)+1)
            float r0 = __builtin_amdgcn_rcpf(__expf(qv + k0) + 1.f);
            float r1 = __builtin_amdgcn_rcpf(__expf(qv + k1) + 1.f);
            e0 = fmaf(wa, r0, e0);
            e1 = fmaf(wa, r1, e1);
        }
        int ta = t0 + sl + tlg, tb = t0 + sl + tlg + 32;
        if (ta < 0 || ta >= SEQ) e0 = -INFINITY;
        if (tb < 0 || tb >= SEQ) e1 = -INFINITY;
        sc[sl * SCS + tlg]      = e0;
        sc[sl * SCS + tlg + 32] = e1;
    }
    __syncthreads();

    // ---- softmax: each 32-lane group owns one row (2 elements/lane) ----
    {
        int lane = tid & 63, wv = tid >> 6;
        int row  = wv * 2 + (lane >> 5);
        int l32  = lane & 31;
        float e0 = sc[row * SCS + l32];
        float e1 = sc[row * SCS + l32 + 32];
        float m = fmaxf(e0, e1);
#pragma unroll
        for (int off = 16; off >= 1; off >>= 1) m = fmaxf(m, __shfl_xor(m, off));
        float p0 = __expf(e0 - m), p1 = __expf(e1 - m);
        float ssum = p0 + p1;
#pragma unroll
        for (int off = 16; off >= 1; off >>= 1) ssum += __shfl_xor(ssum, off);
        float inv = __builtin_amdgcn_rcpf(ssum + EPS);
        sc[row * SCS + l32]      = p0 * inv;
        sc[row * SCS + l32 + 32] = p1 * inv;
    }
    __syncthreads();

    // ---- a-write: 8 rows x 1024 floats, float4 per thread per row ----
    float* arow = aout + ((size_t)(b * SEQ + s0)) * SEQ;
    int i0 = tid << 2;
#pragma unroll
    for (int r = 0; r < TS; ++r) {
        int lowerAbs = s0 + r - HALFW;
        int d = i0 - lowerAbs;          // window offset of component .x
        float4 v4 = {0.f, 0.f, 0.f, 0.f};
        if (d > -4 && d < WIDTH) {
            const float* row = sc + r * SCS;
            if (d >= 0     && d     < WIDTH) v4.x = row[d];
            if (d + 1 >= 0 && d + 1 < WIDTH) v4.y = row[d + 1];
            if (d + 2 >= 0 && d + 2 < WIDTH) v4.z = row[d + 2];
            if (d + 3 >= 0 && d + 3 < WIDTH) v4.w = row[d + 3];
        }
        *reinterpret_cast<float4*>(arow + (size_t)r * SEQ + i0) = v4;
    }
}

// ---------------- Kernel 3: v = a @ x over the window --------------------
__global__ __launch_bounds__(256) void v_kernel(
    const float* __restrict__ x, const float* __restrict__ aout,
    float* __restrict__ out)
{
    __shared__ float xt[CH * XS];       // x[b][c][t0+tt]
    __shared__ float sc[TS * SCS];      // a-window, matches kernel-2 layout

    int tid = threadIdx.x;
    int blk = blockIdx.x;
    int b   = blk >> 7;
    int s0  = (blk & 127) << 3;
    int t0  = s0 - HALFW;

    const float* xb = x + (size_t)b * CH * SEQ;

    if (t0 >= 0 && t0 + TT <= SEQ) {
        // interior: vectorized, 64 rows x 18 float4 = 1152 loads
#pragma unroll
        for (int i = 0; i < 5; ++i) {
            int idx = i * 256 + tid;
            if (idx < CH * 18) {
                int c = idx / 18, p = idx - c * 18;
                float4 v4 = *reinterpret_cast<const float4*>(xb + c * SEQ + t0 + (p << 2));
                *reinterpret_cast<float4*>(&xt[c * XS + (p << 2)]) = v4;
            }
        }
    } else {
#pragma unroll
        for (int i = 0; i < 18; ++i) {  // 64*72 = 4608 = 18*256
            int idx = i * 256 + tid;
            int c = idx / TT, tt = idx - c * TT;
            int t = t0 + tt; t = t < 0 ? 0 : (t >= SEQ ? SEQ - 1 : t);
            xt[c * XS + tt] = xb[c * SEQ + t];
        }
    }

    // stage a-window: sc[r][j] = a[s0+r][t0+r+j], zero outside [0,SEQ)
    {
        const float* ab = aout + ((size_t)(b * SEQ + s0)) * SEQ;
#pragma unroll
        for (int i = 0; i < 2; ++i) {   // 8*64 = 512 = 2*256
            int idx = i * 256 + tid;
            int r = idx >> 6, j = idx & 63;
            int t = t0 + r + j;
            float av = (t >= 0 && t < SEQ) ? ab[(size_t)r * SEQ + t] : 0.f;
            sc[r * SCS + j] = av;
        }
    }
    __syncthreads();

    // ---- v: thread -> (sl = tid&7, c = 2*(tid>>3)+{0,1}) ----
    {
        int slv = tid & 7, c0 = (tid >> 3) << 1;
        float acc0 = 0.f, acc1 = 0.f;
        const float* x0 = xt + c0 * XS + slv;
        const float* x1 = x0 + XS;
        const float* ar = sc + slv * SCS;
#pragma unroll
        for (int j = 0; j < WIDTH; ++j) {
            float av = ar[j];
            acc0 = fmaf(av, x0[j], acc0);
            acc1 = fmaf(av, x1[j], acc1);
        }
        out[((size_t)(b * CH + c0)) * SEQ + s0 + slv]     = acc0;
        out[((size_t)(b * CH + c0 + 1)) * SEQ + s0 + slv] = acc1;
    }
}

extern "C" void kernel_launch(void* const* d_in, const int* in_sizes, int n_in,
                              void* d_out, int out_size, void* d_ws, size_t ws_size,
                              hipStream_t stream) {
    const float* x    = (const float*)d_in[0];
    const float* Wt   = (const float*)d_in[1];
    const float* Wx   = (const float*)d_in[2];
    const float* Wa_w = (const float*)d_in[3];
    // Wa_b (d_in[4]) is a per-row constant shift -> cancels in softmax
    const float* bh   = (const float*)d_in[5];
    float* out = (float*)d_out;

    // q2/k2 live in the v-region of out; overwritten by v_kernel at the end.
    float* q2   = out;                                   // (B, U, S)
    float* k2   = out + (size_t)BATCH * UNITS * SEQ;     // (B, U, S)
    float* aout = out + (size_t)BATCH * CH * SEQ;        // (B, S, S)

    qk_kernel<<<BATCH * UNITS, 256, 0, stream>>>(x, Wt, Wx, bh, q2, k2);
    score_kernel<<<BATCH * (SEQ / TS), 256, 0, stream>>>(q2, k2, Wa_w, aout);
    v_kernel<<<BATCH * (SEQ / TS), 256, 0, stream>>>(x, aout, out);
}

// Round 3
// 79.211 us; speedup vs baseline: 1.0564x; 1.0564x over previous
//
#include <hip/hip_runtime.h>
#include <cstddef>
#include <cmath>

#define SEQ    1024
#define CH     64
#define UNITS  32
#define WIDTH  64
#define HALFW  32
#define BATCH  4
#define EPS    1e-7f

#define TS     8          // s-tile per block
#define TT     72         // t-extent staged: TS + 63, padded to 72
#define XS     76         // LDS row stride: float4-aligned; 76r%32 -> 2-way alias (free)
#define SCS    65         // LDS row stride for score tile

// Learned (R2): the 256 MiB d_ws poison-fill runs UNCONDITIONALLY every
// iteration (~2 x 42 us = the measured floor), so using d_ws is free.
// Structure: fused 2-kernel (avoids the 16 MiB a re-read of the split plan).
//   k1: x -> q2 = 2*(q+bh), k2 = 2*k   (d_ws)
//   k2: q2,k2,x -> a (out) + v (out), fused
// Inner loop identity: score = const + sum_u (-2*wa_u) * rcp(exp(2z)+1);
// the per-row constant (S_wa + Wa_b) cancels in softmax -> never computed.

// ---------------- Kernel 1: scaled q/k projections ----------------
__global__ __launch_bounds__(256) void qk_kernel(
    const float* __restrict__ x, const float* __restrict__ Wt,
    const float* __restrict__ Wx, const float* __restrict__ bh,
    float* __restrict__ q2, float* __restrict__ k2)
{
    int bu = blockIdx.x;                 // b*UNITS + u
    int u  = bu & (UNITS - 1);
    int b  = bu >> 5;
    int s4 = (int)threadIdx.x << 2;

    const float* wt = Wt + u * CH;
    const float* wx = Wx + u * CH;
    const float* xb = x + (size_t)b * CH * SEQ + s4;

    float4 qa = {0.f, 0.f, 0.f, 0.f};
    float4 ka = {0.f, 0.f, 0.f, 0.f};
#pragma unroll
    for (int c = 0; c < CH; ++c) {
        float4 xv = *reinterpret_cast<const float4*>(xb + (size_t)c * SEQ);
        float wtc = wt[c], wxc = wx[c];
        qa.x = fmaf(xv.x, wtc, qa.x); qa.y = fmaf(xv.y, wtc, qa.y);
        qa.z = fmaf(xv.z, wtc, qa.z); qa.w = fmaf(xv.w, wtc, qa.w);
        ka.x = fmaf(xv.x, wxc, ka.x); ka.y = fmaf(xv.y, wxc, ka.y);
        ka.z = fmaf(xv.z, wxc, ka.z); ka.w = fmaf(xv.w, wxc, ka.w);
    }
    float bhu = bh[u];
    qa.x = 2.f * (qa.x + bhu); qa.y = 2.f * (qa.y + bhu);
    qa.z = 2.f * (qa.z + bhu); qa.w = 2.f * (qa.w + bhu);
    ka.x *= 2.f; ka.y *= 2.f; ka.z *= 2.f; ka.w *= 2.f;

    size_t o = (size_t)bu * SEQ + s4;
    *reinterpret_cast<float4*>(q2 + o) = qa;
    *reinterpret_cast<float4*>(k2 + o) = ka;
}

// ------- Kernel 2 (fused): scores + softmax + a-write + v-write ----------
__global__ __launch_bounds__(256) void attn_kernel(
    const float* __restrict__ x,
    const float* __restrict__ q2, const float* __restrict__ k2,
    const float* __restrict__ Wa_w, float* __restrict__ out)
{
    __shared__ float xt[CH * XS];       // x[b][c][t0+tt]
    __shared__ float kt[UNITS * XS];    // k2[b][u][t0+tt]
    __shared__ float qt[UNITS * TS];    // q2[b][u][s0+sl]
    __shared__ float sc[TS * SCS];      // scores -> a
    __shared__ float wa_s[UNITS];       // -2*wa

    int tid = threadIdx.x;
    int blk = blockIdx.x;
    int b   = blk >> 7;                 // SEQ/TS = 128 tiles per batch
    int s0  = (blk & 127) << 3;
    int t0  = s0 - HALFW;

    const float* xb = x  + (size_t)b * CH * SEQ;
    const float* qb = q2 + (size_t)b * UNITS * SEQ;
    const float* kb = k2 + (size_t)b * UNITS * SEQ;

    // ---- stage ----
    {
        int u = tid >> 3, sl = tid & 7;
        qt[u * TS + sl] = qb[u * SEQ + s0 + sl];
    }
    if (tid < UNITS) wa_s[tid] = -2.f * Wa_w[tid];

    if (t0 >= 0 && t0 + TT <= SEQ) {
        // interior tiles: float4 staging. kt: 32x18, xt: 64x18 float4s.
#pragma unroll
        for (int i = 0; i < 3; ++i) {
            int idx = i * 256 + tid;
            if (idx < UNITS * 18) {
                int u = idx / 18, p = idx - u * 18;
                float4 v4 = *reinterpret_cast<const float4*>(kb + u * SEQ + t0 + (p << 2));
                *reinterpret_cast<float4*>(&kt[u * XS + (p << 2)]) = v4;
            }
        }
#pragma unroll
        for (int i = 0; i < 5; ++i) {
            int idx = i * 256 + tid;
            if (idx < CH * 18) {
                int c = idx / 18, p = idx - c * 18;
                float4 v4 = *reinterpret_cast<const float4*>(xb + c * SEQ + t0 + (p << 2));
                *reinterpret_cast<float4*>(&xt[c * XS + (p << 2)]) = v4;
            }
        }
    } else {
        // edge tiles (8 per batch): scalar with clamp
#pragma unroll
        for (int i = 0; i < 9; ++i) {   // 32*72 = 2304 = 9*256
            int idx = i * 256 + tid;
            int u = idx / TT, tt = idx - u * TT;
            int t = t0 + tt; t = t < 0 ? 0 : (t >= SEQ ? SEQ - 1 : t);
            kt[u * XS + tt] = kb[u * SEQ + t];
        }
#pragma unroll
        for (int i = 0; i < 18; ++i) {  // 64*72 = 4608 = 18*256
            int idx = i * 256 + tid;
            int c = idx / TT, tt = idx - c * TT;
            int t = t0 + tt; t = t < 0 ? 0 : (t >= SEQ ? SEQ - 1 : t);
            xt[c * XS + tt] = xb[c * SEQ + t];
        }
    }
    __syncthreads();

    // ---- scores: thread -> (sl = tid>>5, tl in {tid&31, +32}) ----
    {
        int sl = tid >> 5, tlg = tid & 31;
        float e0 = 0.f, e1 = 0.f;
#pragma unroll
        for (int u = 0; u < UNITS; ++u) {
            float qv = qt[u * TS + sl];
            float k0 = kt[u * XS + sl + tlg];
            float k1 = kt[u * XS + sl + tlg + 32];
            float wa = wa_s[u];
            // score += wa_u * tanh(z)  ==  const + (-2*wa_u) * rcp(exp(2z)+1)
            float r0 = __builtin_amdgcn_rcpf(__expf(qv + k0) + 1.f);
            float r1 = __builtin_amdgcn_rcpf(__expf(qv + k1) + 1.f);
            e0 = fmaf(wa, r0, e0);
            e1 = fmaf(wa, r1, e1);
        }
        int ta = t0 + sl + tlg, tb = t0 + sl + tlg + 32;
        if (ta < 0 || ta >= SEQ) e0 = -INFINITY;
        if (tb < 0 || tb >= SEQ) e1 = -INFINITY;
        sc[sl * SCS + tlg]      = e0;
        sc[sl * SCS + tlg + 32] = e1;
    }
    __syncthreads();

    // ---- softmax: each 32-lane group owns one row (2 elements/lane) ----
    {
        int lane = tid & 63, wv = tid >> 6;
        int row  = wv * 2 + (lane >> 5);
        int l32  = lane & 31;
        float e0 = sc[row * SCS + l32];
        float e1 = sc[row * SCS + l32 + 32];
        float m = fmaxf(e0, e1);
#pragma unroll
        for (int off = 16; off >= 1; off >>= 1) m = fmaxf(m, __shfl_xor(m, off));
        float p0 = __expf(e0 - m), p1 = __expf(e1 - m);
        float ssum = p0 + p1;
#pragma unroll
        for (int off = 16; off >= 1; off >>= 1) ssum += __shfl_xor(ssum, off);
        float inv = __builtin_amdgcn_rcpf(ssum + EPS);
        sc[row * SCS + l32]      = p0 * inv;
        sc[row * SCS + l32 + 32] = p1 * inv;
    }
    __syncthreads();

    // ---- a-write: 8 rows x 1024 floats, float4 per thread per row ----
    float* arow = out + (size_t)BATCH * CH * SEQ + ((size_t)(b * SEQ + s0)) * SEQ;
    int i0 = tid << 2;
#pragma unroll
    for (int r = 0; r < TS; ++r) {
        int lowerAbs = s0 + r - HALFW;
        int d = i0 - lowerAbs;          // window offset of component .x
        float4 v4 = {0.f, 0.f, 0.f, 0.f};
        if (d > -4 && d < WIDTH) {
            const float* row = sc + r * SCS;
            if (d >= 0     && d     < WIDTH) v4.x = row[d];
            if (d + 1 >= 0 && d + 1 < WIDTH) v4.y = row[d + 1];
            if (d + 2 >= 0 && d + 2 < WIDTH) v4.z = row[d + 2];
            if (d + 3 >= 0 && d + 3 < WIDTH) v4.w = row[d + 3];
        }
        *reinterpret_cast<float4*>(arow + (size_t)r * SEQ + i0) = v4;
    }

    // ---- v: thread -> (sl = tid&7, c = 2*(tid>>3)+{0,1}) ----
    {
        int slv = tid & 7, c0 = (tid >> 3) << 1;
        float acc0 = 0.f, acc1 = 0.f;
        const float* x0 = xt + c0 * XS + slv;
        const float* x1 = x0 + XS;
        const float* ar = sc + slv * SCS;
#pragma unroll
        for (int j = 0; j < WIDTH; ++j) {
            float av = ar[j];
            acc0 = fmaf(av, x0[j], acc0);
            acc1 = fmaf(av, x1[j], acc1);
        }
        out[((size_t)(b * CH + c0)) * SEQ + s0 + slv]     = acc0;
        out[((size_t)(b * CH + c0 + 1)) * SEQ + s0 + slv] = acc1;
    }
}

extern "C" void kernel_launch(void* const* d_in, const int* in_sizes, int n_in,
                              void* d_out, int out_size, void* d_ws, size_t ws_size,
                              hipStream_t stream) {
    const float* x    = (const float*)d_in[0];
    const float* Wt   = (const float*)d_in[1];
    const float* Wx   = (const float*)d_in[2];
    const float* Wa_w = (const float*)d_in[3];
    // Wa_b (d_in[4]) is a per-row constant shift -> cancels in softmax
    const float* bh   = (const float*)d_in[5];
    float* out = (float*)d_out;

    // d_ws poison is unconditional (R2 evidence) -> using it is free.
    float* q2 = (float*)d_ws;                          // (B, U, S)
    float* k2 = q2 + (size_t)BATCH * UNITS * SEQ;      // (B, U, S)

    qk_kernel<<<BATCH * UNITS, 256, 0, stream>>>(x, Wt, Wx, bh, q2, k2);
    attn_kernel<<<BATCH * (SEQ / TS), 256, 0, stream>>>(x, q2, k2, Wa_w, out);
}